// Round 11
// baseline (143.977 us; speedup 1.0000x reference)
//
#include <hip/hip_runtime.h>
#include <hip/hip_bf16.h>

// TransposedLocallyConnected2D: out[b,o,l] = sum_d U[b,d,l] * W[d,l,o] + bias[o,l]
//   B=64, C=64, OC=128, L=1024, D=576 (d = c*9 + ii*3 + jj). Per-l 64x128x576 GEMM.
//
// R11: ws round-trip + out_kernel DELETED (the only lever with verified 1:1
// traffic->time response, R8). mfma_fused:
//  - grid 256 = 64 l-groups (lg, 16 consecutive l) x 4 o-quarters (oq).
//    Swizzle: xcd = blk&7, oq = (blk>>3)&3, hi = blk>>5; lg = xcd*8 + hi.
//    -> 4 uA-sharing oq-siblings are CONSECUTIVE on the SAME XCD (L2 reuse);
//    each XCD owns lg 8x..8x+7 (contiguous 128 l) for W page locality.
//  - 1024 thr = 16 waves; wave wvn owns l = lg*16+wvn, o = 32oq+16n+r (n=0,1).
//    k-loop body verbatim R10 (verified): saddr bases, u32 lane offsets,
//    v_cvt_pk_bf16_f32, 8 MFMA/kt, full-K 18 kt.
//  - epilogue: 4 mt-phases through 32KB LDS tile [o' 32][l 16][b 16] f32;
//    write acc f32x4 (q contiguous); read 4x b32 along l; store full-line
//    [b][o][l]-order f32x4 + fused bias. Every 64B out line completed in-block.
//
// uA byte layout (R7-R10 verified):
//   frag(mt,kt,g,r | l) = U[b=16mt+r][k=32kt+8g+e][l], e=0..7 (bf16 us8)
//   at oh*2359296 + ((mt*18)+kt... : mt*589824 + kt*32768 + g*8192 + (ow*16+r)*16.

typedef __attribute__((ext_vector_type(8))) short bf16x8;
typedef __attribute__((ext_vector_type(4))) float f32x4;
typedef __attribute__((ext_vector_type(4))) unsigned short us4;
typedef __attribute__((ext_vector_type(8))) unsigned short us8;

__device__ __forceinline__ unsigned short f2bf(float f) {
    union { __hip_bfloat16 h; unsigned short u; } cv;
    cv.h = __float2bfloat16(f);
    return cv.u;
}

// ---------------------------------------------------------------- kernel 1
// grid 256: blk -> ch (c-half), bg (b-quarter = mt), oh.  (R7-R10 verified)
__global__ __launch_bounds__(256, 1)
void u_kernel(const float* __restrict__ x, unsigned short* __restrict__ uA)
{
    __shared__ unsigned short xs[3 * 32 * 16 * 36];   // [y][c][b][32z + 4 pad]

    const int blk = blockIdx.x;
    const int ch = blk & 1;          // c in [32ch, 32ch+32)
    const int bg = (blk >> 1) & 3;   // b in [16bg, 16bg+16)  (mt = bg)
    const int oh = blk >> 3;
    const int t  = threadIdx.x;

    // ---- stage x chunk: 16b x 32c x 3y x 32z, fully coalesced float4
    #pragma unroll
    for (int y = 0; y < 3; ++y) {
        const int yg = oh - 1 + y;
        const bool rowok = (unsigned)yg < 32u;   // block-uniform
        #pragma unroll
        for (int j = 0; j < 16; ++j) {
            const int idx2 = t + 256 * j;
            const int z4 = idx2 & 7;
            const int cl = (idx2 >> 3) & 31;
            const int bl = idx2 >> 8;
            float4 v = {0.f, 0.f, 0.f, 0.f};
            if (rowok)
                v = *(const float4*)(x + ((((16 * bg + bl) * 64 + 32 * ch + cl) * 32 + yg) << 5) + 4 * z4);
            *(us4*)&xs[((y * 32 + cl) * 16 + bl) * 36 + 4 * z4] =
                (us4){f2bf(v.x), f2bf(v.y), f2bf(v.z), f2bf(v.w)};
        }
    }
    __syncthreads();

    // ---- gather: item (bl = t&15, ow = t>>4 + 16p)  -> 1KB-contiguous wave stores
    const int bl = t & 15;
    #pragma unroll
    for (int p = 0; p < 2; ++p) {
        const int ow = (t >> 4) + 16 * p;
        #pragma unroll
        for (int cc = 0; cc < 2; ++cc) {
            us8 arr[18];
            #pragma unroll
            for (int c16 = 0; c16 < 16; ++c16) {
                const int c = cc * 16 + c16;
                #pragma unroll
                for (int ii = 0; ii < 3; ++ii) {
                    const unsigned short* xr = &xs[((ii * 32 + c) * 16 + bl) * 36];
                    const unsigned short vm = (ow > 0)  ? xr[ow - 1] : (unsigned short)0;
                    const unsigned short v0 = xr[ow];
                    const unsigned short vp = (ow < 31) ? xr[ow + 1] : (unsigned short)0;
                    const int f = c16 * 9 + ii * 3;      // compile-time after unroll
                    arr[(f + 0) >> 3][(f + 0) & 7] = vm;
                    arr[(f + 1) >> 3][(f + 1) & 7] = v0;
                    arr[(f + 2) >> 3][(f + 2) & 7] = vp;
                }
            }
            // ks = 36ch + 18cc + j; kt = ks>>2, g = ks&3
            char* base = (char*)uA + (size_t)(oh * 4 + bg) * 589824 + (ow * 16 + bl) * 16;
            #pragma unroll
            for (int j = 0; j < 18; ++j) {
                const int ks = 36 * ch + 18 * cc + j;
                *(us8*)(base + (size_t)(ks >> 2) * 32768 + (size_t)(ks & 3) * 8192) = arr[j];
            }
        }
    }
}

// ---------------------------------------------------------------- kernel 2
// grid 256 = (xcd, oq, hi); block 1024 = 16 waves; wave wvn: l = lg*16 + wvn.
__global__ __launch_bounds__(1024, 1)
void mfma_fused(const unsigned short* __restrict__ uA,
                const float* __restrict__ w,
                const float* __restrict__ bias,
                float* __restrict__ out)
{
    __shared__ float Ls[32 * 16 * 16];   // [o' 32][l~ 16][b~ 16], 32 KB

    const int blk  = blockIdx.x;
    const int xcd  = blk & 7;
    const int oq   = (blk >> 3) & 3;     // o-quarter: o0 = 32*oq
    const int hi   = blk >> 5;           // 0..7
    const int lg   = xcd * 8 + hi;       // 0..63, 16 l's per lg
    const int tid  = threadIdx.x;
    const int lane = tid & 63;
    const int wvn  = tid >> 6;           // 0..15 -> l = lg*16 + wvn
    const int r    = lane & 15;
    const int g    = lane >> 4;
    const int l    = lg * 16 + wvn;
    const int oh   = lg >> 1;                    // block-uniform
    const int ow   = ((lg & 1) << 4) + wvn;      // 0..31
    const int o0   = 32 * oq;

    // uniform SGPR bases (stepped by compile-time constants per kt)
    const char* ubase = (const char*)uA + (size_t)oh * 2359296;   // oh * 4*18*32768
    const char* wbase = (const char*)w  + (size_t)l * 512;

    // per-lane u32 offsets, constant through the k-loop (R9/R10-verified form)
    const unsigned uoff = (unsigned)(g * 8192 + (ow * 16 + r) * 16);
    unsigned woff[2][8];
    #pragma unroll
    for (int n = 0; n < 2; ++n)
        #pragma unroll
        for (int i = 0; i < 8; ++i)
            woff[n][i] = (unsigned)((8 * g + i) * 524288 + (o0 + 16 * n + r) * 4);

    f32x4 acc[4][2];
    #pragma unroll
    for (int mt = 0; mt < 4; ++mt) {
        acc[mt][0] = (f32x4){0.f, 0.f, 0.f, 0.f};
        acc[mt][1] = (f32x4){0.f, 0.f, 0.f, 0.f};
    }

    #pragma unroll
    for (int ktl = 0; ktl < 18; ++ktl) {
        const char* ub_kt = ubase + ktl * 32768;
        const char* wb_kt = wbase + (size_t)ktl * 16777216;       // 32*131072*4

        bf16x8 cu[4];
        #pragma unroll
        for (int mt = 0; mt < 4; ++mt)
            cu[mt] = *(const bf16x8*)(ub_kt + mt * 589824 + uoff);

        float wf[2][8];
        #pragma unroll
        for (int n = 0; n < 2; ++n)
            #pragma unroll
            for (int i = 0; i < 8; ++i)
                wf[n][i] = *(const float*)(wb_kt + woff[n][i]);

        union { unsigned u[4]; bf16x8 b; } cb[2];
        #pragma unroll
        for (int n = 0; n < 2; ++n)
            #pragma unroll
            for (int j = 0; j < 4; ++j)
                asm("v_cvt_pk_bf16_f32 %0, %1, %2"
                    : "=v"(cb[n].u[j]) : "v"(wf[n][2 * j]), "v"(wf[n][2 * j + 1]));

        #pragma unroll
        for (int mt = 0; mt < 4; ++mt) {
            acc[mt][0] = __builtin_amdgcn_mfma_f32_16x16x32_bf16(cu[mt], cb[0].b, acc[mt][0], 0, 0, 0);
            acc[mt][1] = __builtin_amdgcn_mfma_f32_16x16x32_bf16(cu[mt], cb[1].b, acc[mt][1], 0, 0, 0);
        }
    }

    // ---- epilogue: 4 mt-phases; acc[p][n] elem q -> b = 16p+4g+q, o = o0+16n+r,
    //      l = lg*16 + wvn.  LDS tile [o'][l~][b~]: fidx = (o'*16 + l~)*16 + b~.
    const int rb   = tid & 15;            // b~ for read/store
    const int ro   = (tid >> 4) & 31;     // o' for read/store
    const int lh   = tid >> 9;            // 0..1
    #pragma unroll
    for (int p = 0; p < 4; ++p) {
        __syncthreads();   // Ls free (prev phase reads done)
        #pragma unroll
        for (int n = 0; n < 2; ++n) {
            const int fidx = (((16 * n + r) * 16) + wvn) * 16 + 4 * g;
            *(f32x4*)&Ls[fidx] = acc[p][n];
        }
        __syncthreads();
        #pragma unroll
        for (int s = 0; s < 2; ++s) {
            const int l4 = lh * 2 + s;            // 0..3 -> l = lg*16 + l4*4 + j
            f32x4 v;
            #pragma unroll
            for (int j = 0; j < 4; ++j)
                v[j] = Ls[(ro * 16 + l4 * 4 + j) * 16 + rb];
            const int b = 16 * p + rb;
            const int o = o0 + ro;
            const int lbase = lg * 16 + l4 * 4;
            const f32x4 bz = *(const f32x4*)(bias + (o << 10) + lbase);
            v += bz;
            *(f32x4*)(out + (((size_t)(b * 128 + o)) << 10) + lbase) = v;
        }
    }
}

// ---------------------------------------------------------------- fp32 fallback (R1-verified)
__global__ __launch_bounds__(256, 4)
void lc2d_fp32(const float* __restrict__ x,
               const float* __restrict__ w,
               const float* __restrict__ bias,
               float* __restrict__ out)
{
    __shared__ float Us[36][68];
    __shared__ float Ws[36][128];
    const int blk = blockIdx.x;
    const int l  = ((blk & 7) << 7) | (blk >> 3);
    const int oh = l >> 5, ow = l & 31;
    const int tid = threadIdx.x;
    const int tx = tid & 15, ty = tid >> 4;
    const int sb = tid >> 2, sc = tid & 3;

    float acc[4][8];
    #pragma unroll
    for (int i = 0; i < 4; ++i)
        #pragma unroll
        for (int j = 0; j < 8; ++j) acc[i][j] = 0.f;

    for (int chn = 0; chn < 16; ++chn) {
        const int c0 = chn * 4;
        const float* xb = x + ((size_t)(sb * 64 + c0 + sc) << 10);
        #pragma unroll
        for (int ii = 0; ii < 3; ++ii) {
            const int y = oh + ii - 1;
            const bool yok = ((unsigned)y < 32u);
            #pragma unroll
            for (int jj = 0; jj < 3; ++jj) {
                const int z = ow + jj - 1;
                float v = 0.f;
                if (yok && ((unsigned)z < 32u)) v = xb[(y << 5) + z];
                Us[sc * 9 + ii * 3 + jj][sb] = v;
            }
        }
        const int dbase = c0 * 9;
        #pragma unroll
        for (int it = 0; it < 5; ++it) {
            const int idx = tid + it * 256;
            if (idx < 36 * 32) {
                const int kk = idx >> 5, o4 = idx & 31;
                const float4 v = *reinterpret_cast<const float4*>(
                    w + (((size_t)(dbase + kk) * 1024 + l) * 128 + o4 * 4));
                *reinterpret_cast<float4*>(&Ws[kk][o4 * 4]) = v;
            }
        }
        __syncthreads();
        #pragma unroll 6
        for (int kk = 0; kk < 36; ++kk) {
            const float4 ub = *reinterpret_cast<const float4*>(&Us[kk][ty * 4]);
            const float4 wa = *reinterpret_cast<const float4*>(&Ws[kk][tx * 4]);
            const float4 wb = *reinterpret_cast<const float4*>(&Ws[kk][tx * 4 + 64]);
            const float u[4]  = {ub.x, ub.y, ub.z, ub.w};
            const float a[4]  = {wa.x, wa.y, wa.z, wa.w};
            const float b2[4] = {wb.x, wb.y, wb.z, wb.w};
            #pragma unroll
            for (int bi = 0; bi < 4; ++bi)
                #pragma unroll
                for (int oi = 0; oi < 4; ++oi) {
                    acc[bi][oi]     += u[bi] * a[oi];
                    acc[bi][4 + oi] += u[bi] * b2[oi];
                }
        }
        __syncthreads();
    }

    float bs[8];
    #pragma unroll
    for (int oi = 0; oi < 4; ++oi) {
        bs[oi]     = bias[((tx * 4 + oi) << 10) + l];
        bs[4 + oi] = bias[((tx * 4 + 64 + oi) << 10) + l];
    }
    #pragma unroll
    for (int bi = 0; bi < 4; ++bi) {
        const int b = ty * 4 + bi;
        #pragma unroll
        for (int oi = 0; oi < 4; ++oi) {
            out[((b * 128 + tx * 4 + oi) << 10) + l]      = acc[bi][oi]     + bs[oi];
            out[((b * 128 + tx * 4 + 64 + oi) << 10) + l] = acc[bi][4 + oi] + bs[4 + oi];
        }
    }
}

// ---------------------------------------------------------------- launch
extern "C" void kernel_launch(void* const* d_in, const int* in_sizes, int n_in,
                              void* d_out, int out_size, void* d_ws, size_t ws_size,
                              hipStream_t stream) {
    const float* x    = (const float*)d_in[0];
    const float* w    = (const float*)d_in[1];
    const float* bias = (const float*)d_in[2];
    float* out        = (float*)d_out;

    const size_t UA_BYTES = 75497472ull;   // 32*4*18*4*8192

    if (d_ws && ws_size >= UA_BYTES) {
        unsigned short* uab = (unsigned short*)d_ws;
        u_kernel<<<dim3(256), dim3(256), 0, stream>>>(x, uab);
        mfma_fused<<<dim3(256), dim3(1024), 0, stream>>>(uab, w, bias, out);
    } else {
        lc2d_fp32<<<dim3(1024), dim3(256), 0, stream>>>(x, w, bias, out);
    }
}

// Round 12
// 127.909 us; speedup vs baseline: 1.1256x; 1.1256x over previous
//
#include <hip/hip_runtime.h>
#include <hip/hip_bf16.h>

// TransposedLocallyConnected2D: out[b,o,l] = sum_d U[b,d,l] * W[d,l,o] + bias[o,l]
//   B=64, C=64, OC=128, L=1024, D=576 (d = c*9 + ii*3 + jj). Per-l 64x128x576 GEMM.
//
// R12: R9/R10/R11 nulls => the wall is the SHAPE of the W read (16 scalar-dword
// loads/kt/wave, 4x64B scattered segments, consumer-gated). Fix: cooperative LDS
// staging with copy-kernel-shaped loads:
//  - per kt the block stages W[32d][16l][32o] (64KB f32) via 4 dwordx4/thread
//    (each instruction: 8 dense 128B segments), 2-tiles-ahead reg pipeline
//    (explicit rA/rB rotation, issue-early/write-late), ONE barrier per kt.
//  - cvt f32->bf16 in regs; transpose into fragment-order LDS: slot s = nt*64 +
//    g*16 + rf (rf = o-local&15), column c = l~ ^ (s&15) (XOR swizzle), elem e=d&7.
//    Read: wave wvn lane(r,g): ushort ofs = s*128 + (wvn^r)*8, bf16x8 (2-way free).
//  - B-fragment bytes identical to R11's verified cvt_pk fragments (e <-> d=8g+e).
//  - uA path, acc layout, epilogue, u_kernel, fallback: verbatim R11 (verified).

typedef __attribute__((ext_vector_type(8))) short bf16x8;
typedef __attribute__((ext_vector_type(4))) float f32x4;
typedef __attribute__((ext_vector_type(4))) unsigned short us4;
typedef __attribute__((ext_vector_type(8))) unsigned short us8;

__device__ __forceinline__ unsigned short f2bf(float f) {
    union { __hip_bfloat16 h; unsigned short u; } cv;
    cv.h = __float2bfloat16(f);
    return cv.u;
}

// ---------------------------------------------------------------- kernel 1
// grid 256: blk -> ch (c-half), bg (b-quarter = mt), oh.  (R7-R11 verified)
__global__ __launch_bounds__(256, 1)
void u_kernel(const float* __restrict__ x, unsigned short* __restrict__ uA)
{
    __shared__ unsigned short xs[3 * 32 * 16 * 36];   // [y][c][b][32z + 4 pad]

    const int blk = blockIdx.x;
    const int ch = blk & 1;          // c in [32ch, 32ch+32)
    const int bg = (blk >> 1) & 3;   // b in [16bg, 16bg+16)  (mt = bg)
    const int oh = blk >> 3;
    const int t  = threadIdx.x;

    #pragma unroll
    for (int y = 0; y < 3; ++y) {
        const int yg = oh - 1 + y;
        const bool rowok = (unsigned)yg < 32u;   // block-uniform
        #pragma unroll
        for (int j = 0; j < 16; ++j) {
            const int idx2 = t + 256 * j;
            const int z4 = idx2 & 7;
            const int cl = (idx2 >> 3) & 31;
            const int bl = idx2 >> 8;
            float4 v = {0.f, 0.f, 0.f, 0.f};
            if (rowok)
                v = *(const float4*)(x + ((((16 * bg + bl) * 64 + 32 * ch + cl) * 32 + yg) << 5) + 4 * z4);
            *(us4*)&xs[((y * 32 + cl) * 16 + bl) * 36 + 4 * z4] =
                (us4){f2bf(v.x), f2bf(v.y), f2bf(v.z), f2bf(v.w)};
        }
    }
    __syncthreads();

    const int bl = t & 15;
    #pragma unroll
    for (int p = 0; p < 2; ++p) {
        const int ow = (t >> 4) + 16 * p;
        #pragma unroll
        for (int cc = 0; cc < 2; ++cc) {
            us8 arr[18];
            #pragma unroll
            for (int c16 = 0; c16 < 16; ++c16) {
                const int c = cc * 16 + c16;
                #pragma unroll
                for (int ii = 0; ii < 3; ++ii) {
                    const unsigned short* xr = &xs[((ii * 32 + c) * 16 + bl) * 36];
                    const unsigned short vm = (ow > 0)  ? xr[ow - 1] : (unsigned short)0;
                    const unsigned short v0 = xr[ow];
                    const unsigned short vp = (ow < 31) ? xr[ow + 1] : (unsigned short)0;
                    const int f = c16 * 9 + ii * 3;
                    arr[(f + 0) >> 3][(f + 0) & 7] = vm;
                    arr[(f + 1) >> 3][(f + 1) & 7] = v0;
                    arr[(f + 2) >> 3][(f + 2) & 7] = vp;
                }
            }
            char* base = (char*)uA + (size_t)(oh * 4 + bg) * 589824 + (ow * 16 + bl) * 16;
            #pragma unroll
            for (int j = 0; j < 18; ++j) {
                const int ks = 36 * ch + 18 * cc + j;
                *(us8*)(base + (size_t)(ks >> 2) * 32768 + (size_t)(ks & 3) * 8192) = arr[j];
            }
        }
    }
}

// ---------------------------------------------------------------- kernel 2
// grid 256 = (xcd, oq, hi); 1024 thr = 16 waves; wave wvn: l = lg*16 + wvn.
__global__ __launch_bounds__(1024, 1)
void mfma_fused(const unsigned short* __restrict__ uA,
                const float* __restrict__ w,
                const float* __restrict__ bias,
                float* __restrict__ out)
{
    __shared__ char smem[65536];   // Wbuf[2] 2x32KB bf16; epilogue Ls overlays [0,32KB)
    unsigned short* const wb0 = (unsigned short*)smem;
    unsigned short* const wb1 = (unsigned short*)(smem + 32768);

    const int blk  = blockIdx.x;
    const int xcd  = blk & 7;
    const int oq   = (blk >> 3) & 3;     // o0 = 32*oq
    const int hi   = blk >> 5;
    const int lg   = xcd * 8 + hi;       // 16 l's per lg
    const int tid  = threadIdx.x;
    const int lane = tid & 63;
    const int wvn  = tid >> 6;           // 0..15 -> l = lg*16 + wvn
    const int r    = lane & 15;
    const int g    = lane >> 4;
    const int oh   = lg >> 1;                    // block-uniform
    const int ow   = ((lg & 1) << 4) + wvn;
    const int o0   = 32 * oq;

    // ---- uA addressing (R7-R11 verified)
    const char* ubase = (const char*)uA + (size_t)oh * 2359296;
    const unsigned uoff = (unsigned)(g * 8192 + (ow * 16 + r) * 16);

    // ---- W loader thread mapping: D = t>>7 (e), l~L = (t>>3)&15, o4 = t&7
    const int D   = tid >> 7;            // 0..7 = e
    const int lL  = (tid >> 3) & 15;     // staged l~
    const int o4  = tid & 7;             // 4-float o chunk
    const int ntL = o4 >> 2;
    // global float index for (kt, round rr): (kt*32 + 8rr + D)*131072 + (lg*16+lL)*128 + o0 + o4*4
    const float* wth = w + (size_t)D * 131072 + (lg * 16 + lL) * 128 + o0 + o4 * 4;
    // LDS write (ushort units): s = ntL*64 + rr*16 + rf, rf = (o4&3)*4 + v,
    // c = lL ^ (s&15) = lL ^ rf; ofs = s*128 + c*8 + D
#define WSTORE(BUF, RT)                                                        \
    {   _Pragma("unroll")                                                      \
        for (int rr = 0; rr < 4; ++rr) {                                       \
            _Pragma("unroll")                                                  \
            for (int v = 0; v < 4; ++v) {                                      \
                const int rf = (o4 & 3) * 4 + v;                               \
                const int s  = ntL * 64 + rr * 16 + rf;                        \
                (BUF)[s * 128 + (lL ^ rf) * 8 + D] = f2bf((RT)[rr][v]);        \
            }                                                                  \
        }                                                                      \
    }
#define WLOAD(KT, RT)                                                          \
    {   _Pragma("unroll")                                                      \
        for (int rr = 0; rr < 4; ++rr)                                         \
            (RT)[rr] = *(const f32x4*)(wth + ((size_t)(KT) * 32 + 8 * rr) * 131072); \
    }
#define ULOAD(KT, CU)                                                          \
    {   _Pragma("unroll")                                                      \
        for (int mt = 0; mt < 4; ++mt)                                         \
            (CU)[mt] = *(const bf16x8*)(ubase + (size_t)(KT) * 32768 +         \
                                        (size_t)mt * 589824 + uoff);           \
    }

    // ---- B-fragment read offsets (ushort units): nt slot block + column XOR
    const int rdo0 = (0 * 64 + g * 16 + r) * 128 + ((wvn ^ r) & 15) * 8;
    const int rdo1 = (1 * 64 + g * 16 + r) * 128 + ((wvn ^ r) & 15) * 8;

    f32x4 acc[4][2];
    #pragma unroll
    for (int mt = 0; mt < 4; ++mt) {
        acc[mt][0] = (f32x4){0.f, 0.f, 0.f, 0.f};
        acc[mt][1] = (f32x4){0.f, 0.f, 0.f, 0.f};
    }

    // ---- prologue: 2 W tiles + 2 uA tiles in flight
    f32x4 rA[4], rB[4];
    bf16x8 cuA[4], cuB[4];
    WLOAD(0, rA);
    WLOAD(1, rB);
    ULOAD(0, cuA);
    ULOAD(1, cuB);
    WSTORE(wb0, rA);        // waits only W(0)
    __syncthreads();

    #pragma unroll
    for (int kt = 0; kt < 18; ++kt) {
        // issue W(kt+2) into the reg pair freed last iteration
        if (kt + 2 < 18) {
            if ((kt & 1) == 0) { WLOAD(kt + 2, rA); }
            else               { WLOAD(kt + 2, rB); }
        }
        // cvt+write W(kt+1) into the other LDS buffer (waits its loads only)
        if (kt + 1 < 18) {
            if ((kt & 1) == 0) { WSTORE(wb1, rB); }
            else               { WSTORE(wb0, rA); }
        }
        // compute kt from buf[kt&1]
        {
            const unsigned short* bb = (kt & 1) ? wb1 : wb0;
            const bf16x8 bf0 = *(const bf16x8*)(bb + rdo0);
            const bf16x8 bf1 = *(const bf16x8*)(bb + rdo1);
            #pragma unroll
            for (int mt = 0; mt < 4; ++mt) {
                const bf16x8 cu = (kt & 1) ? cuB[mt] : cuA[mt];
                acc[mt][0] = __builtin_amdgcn_mfma_f32_16x16x32_bf16(cu, bf0, acc[mt][0], 0, 0, 0);
                acc[mt][1] = __builtin_amdgcn_mfma_f32_16x16x32_bf16(cu, bf1, acc[mt][1], 0, 0, 0);
            }
        }
        // refill uA slot just consumed with tile kt+2
        if (kt + 2 < 18) {
            if ((kt & 1) == 0) { ULOAD(kt + 2, cuA); }
            else               { ULOAD(kt + 2, cuB); }
        }
        __syncthreads();
    }
#undef WSTORE
#undef WLOAD
#undef ULOAD

    // ---- epilogue (verbatim R11, verified): 4 mt-phases via LDS [o'32][l~16][b~16]
    float* const Ls = (float*)smem;
    const int rb = tid & 15;
    const int ro = (tid >> 4) & 31;
    const int lh = tid >> 9;
    #pragma unroll
    for (int p = 0; p < 4; ++p) {
        __syncthreads();
        #pragma unroll
        for (int n = 0; n < 2; ++n) {
            const int fidx = (((16 * n + r) * 16) + wvn) * 16 + 4 * g;
            *(f32x4*)&Ls[fidx] = acc[p][n];
        }
        __syncthreads();
        #pragma unroll
        for (int s = 0; s < 2; ++s) {
            const int l4 = lh * 2 + s;
            f32x4 v;
            #pragma unroll
            for (int j = 0; j < 4; ++j)
                v[j] = Ls[(ro * 16 + l4 * 4 + j) * 16 + rb];
            const int b = 16 * p + rb;
            const int o = o0 + ro;
            const int lbase = lg * 16 + l4 * 4;
            const f32x4 bz = *(const f32x4*)(bias + (o << 10) + lbase);
            v += bz;
            *(f32x4*)(out + (((size_t)(b * 128 + o)) << 10) + lbase) = v;
        }
    }
}

// ---------------------------------------------------------------- fp32 fallback (R1-verified)
__global__ __launch_bounds__(256, 4)
void lc2d_fp32(const float* __restrict__ x,
               const float* __restrict__ w,
               const float* __restrict__ bias,
               float* __restrict__ out)
{
    __shared__ float Us[36][68];
    __shared__ float Ws[36][128];
    const int blk = blockIdx.x;
    const int l  = ((blk & 7) << 7) | (blk >> 3);
    const int oh = l >> 5, ow = l & 31;
    const int tid = threadIdx.x;
    const int tx = tid & 15, ty = tid >> 4;
    const int sb = tid >> 2, sc = tid & 3;

    float acc[4][8];
    #pragma unroll
    for (int i = 0; i < 4; ++i)
        #pragma unroll
        for (int j = 0; j < 8; ++j) acc[i][j] = 0.f;

    for (int chn = 0; chn < 16; ++chn) {
        const int c0 = chn * 4;
        const float* xb = x + ((size_t)(sb * 64 + c0 + sc) << 10);
        #pragma unroll
        for (int ii = 0; ii < 3; ++ii) {
            const int y = oh + ii - 1;
            const bool yok = ((unsigned)y < 32u);
            #pragma unroll
            for (int jj = 0; jj < 3; ++jj) {
                const int z = ow + jj - 1;
                float v = 0.f;
                if (yok && ((unsigned)z < 32u)) v = xb[(y << 5) + z];
                Us[sc * 9 + ii * 3 + jj][sb] = v;
            }
        }
        const int dbase = c0 * 9;
        #pragma unroll
        for (int it = 0; it < 5; ++it) {
            const int idx = tid + it * 256;
            if (idx < 36 * 32) {
                const int kk = idx >> 5, o4 = idx & 31;
                const float4 v = *reinterpret_cast<const float4*>(
                    w + (((size_t)(dbase + kk) * 1024 + l) * 128 + o4 * 4));
                *reinterpret_cast<float4*>(&Ws[kk][o4 * 4]) = v;
            }
        }
        __syncthreads();
        #pragma unroll 6
        for (int kk = 0; kk < 36; ++kk) {
            const float4 ub = *reinterpret_cast<const float4*>(&Us[kk][ty * 4]);
            const float4 wa = *reinterpret_cast<const float4*>(&Ws[kk][tx * 4]);
            const float4 wb = *reinterpret_cast<const float4*>(&Ws[kk][tx * 4 + 64]);
            const float u[4]  = {ub.x, ub.y, ub.z, ub.w};
            const float a[4]  = {wa.x, wa.y, wa.z, wa.w};
            const float b2[4] = {wb.x, wb.y, wb.z, wb.w};
            #pragma unroll
            for (int bi = 0; bi < 4; ++bi)
                #pragma unroll
                for (int oi = 0; oi < 4; ++oi) {
                    acc[bi][oi]     += u[bi] * a[oi];
                    acc[bi][4 + oi] += u[bi] * b2[oi];
                }
        }
        __syncthreads();
    }

    float bs[8];
    #pragma unroll
    for (int oi = 0; oi < 4; ++oi) {
        bs[oi]     = bias[((tx * 4 + oi) << 10) + l];
        bs[4 + oi] = bias[((tx * 4 + 64 + oi) << 10) + l];
    }
    #pragma unroll
    for (int bi = 0; bi < 4; ++bi) {
        const int b = ty * 4 + bi;
        #pragma unroll
        for (int oi = 0; oi < 4; ++oi) {
            out[((b * 128 + tx * 4 + oi) << 10) + l]      = acc[bi][oi]     + bs[oi];
            out[((b * 128 + tx * 4 + 64 + oi) << 10) + l] = acc[bi][4 + oi] + bs[4 + oi];
        }
    }
}

// ---------------------------------------------------------------- launch
extern "C" void kernel_launch(void* const* d_in, const int* in_sizes, int n_in,
                              void* d_out, int out_size, void* d_ws, size_t ws_size,
                              hipStream_t stream) {
    const float* x    = (const float*)d_in[0];
    const float* w    = (const float*)d_in[1];
    const float* bias = (const float*)d_in[2];
    float* out        = (float*)d_out;

    const size_t UA_BYTES = 75497472ull;   // 32*4*18*4*8192

    if (d_ws && ws_size >= UA_BYTES) {
        unsigned short* uab = (unsigned short*)d_ws;
        u_kernel<<<dim3(256), dim3(256), 0, stream>>>(x, uab);
        mfma_fused<<<dim3(256), dim3(1024), 0, stream>>>(uab, w, bias, out);
    } else {
        lc2d_fp32<<<dim3(1024), dim3(256), 0, stream>>>(x, w, bias, out);
    }
}

// Round 13
// 125.836 us; speedup vs baseline: 1.1442x; 1.0165x over previous
//
#include <hip/hip_runtime.h>
#include <hip/hip_bf16.h>

// TransposedLocallyConnected2D: out[b,o,l] = sum_d U[b,d,l] * W[d,l,o] + bias[o,l]
//   B=64, C=64, OC=128, L=1024, D=576 (d = c*9 + ii*3 + jj). Per-l 64x128x576 GEMM.
//
// R13: R12 (+coop W staging) confirmed read-shape theory (-16us). Remaining gap
// vs ~65us traffic floor = per-kt barrier drain with 1 block/CU. Fix: 2 blocks/CU
// TLP. Block = 512 thr / 8 waves, covers 8 l x 32 o; grid 512 = (xcd8, oq4, hi16).
//  - W tile/kt = 32d x 8l x 32o staged f32 dwordx4 (8x128B dense segments/instr),
//    2-ahead reg pipeline, cvt->bf16, fragment-order LDS; slot rows padded to
//    144B => ds_read_b128 B-frags are conflict-free-optimal (class=(r&7+wvn)%8).
//  - uA cells verbatim (R7-R12 verified); epilogue Ls stride 132 (bank spread);
//    out-line halves (hi, hi+1 blocks) land on same XCD for L2 write merge.

typedef __attribute__((ext_vector_type(8))) short bf16x8;
typedef __attribute__((ext_vector_type(4))) float f32x4;
typedef __attribute__((ext_vector_type(4))) unsigned short us4;
typedef __attribute__((ext_vector_type(8))) unsigned short us8;

__device__ __forceinline__ unsigned short f2bf(float f) {
    union { __hip_bfloat16 h; unsigned short u; } cv;
    cv.h = __float2bfloat16(f);
    return cv.u;
}

// ---------------------------------------------------------------- kernel 1
// grid 256: blk -> ch (c-half), bg (b-quarter = mt), oh.  (R7-R12 verified)
__global__ __launch_bounds__(256, 1)
void u_kernel(const float* __restrict__ x, unsigned short* __restrict__ uA)
{
    __shared__ unsigned short xs[3 * 32 * 16 * 36];   // [y][c][b][32z + 4 pad]

    const int blk = blockIdx.x;
    const int ch = blk & 1;
    const int bg = (blk >> 1) & 3;
    const int oh = blk >> 3;
    const int t  = threadIdx.x;

    #pragma unroll
    for (int y = 0; y < 3; ++y) {
        const int yg = oh - 1 + y;
        const bool rowok = (unsigned)yg < 32u;
        #pragma unroll
        for (int j = 0; j < 16; ++j) {
            const int idx2 = t + 256 * j;
            const int z4 = idx2 & 7;
            const int cl = (idx2 >> 3) & 31;
            const int bl = idx2 >> 8;
            float4 v = {0.f, 0.f, 0.f, 0.f};
            if (rowok)
                v = *(const float4*)(x + ((((16 * bg + bl) * 64 + 32 * ch + cl) * 32 + yg) << 5) + 4 * z4);
            *(us4*)&xs[((y * 32 + cl) * 16 + bl) * 36 + 4 * z4] =
                (us4){f2bf(v.x), f2bf(v.y), f2bf(v.z), f2bf(v.w)};
        }
    }
    __syncthreads();

    const int bl = t & 15;
    #pragma unroll
    for (int p = 0; p < 2; ++p) {
        const int ow = (t >> 4) + 16 * p;
        #pragma unroll
        for (int cc = 0; cc < 2; ++cc) {
            us8 arr[18];
            #pragma unroll
            for (int c16 = 0; c16 < 16; ++c16) {
                const int c = cc * 16 + c16;
                #pragma unroll
                for (int ii = 0; ii < 3; ++ii) {
                    const unsigned short* xr = &xs[((ii * 32 + c) * 16 + bl) * 36];
                    const unsigned short vm = (ow > 0)  ? xr[ow - 1] : (unsigned short)0;
                    const unsigned short v0 = xr[ow];
                    const unsigned short vp = (ow < 31) ? xr[ow + 1] : (unsigned short)0;
                    const int f = c16 * 9 + ii * 3;
                    arr[(f + 0) >> 3][(f + 0) & 7] = vm;
                    arr[(f + 1) >> 3][(f + 1) & 7] = v0;
                    arr[(f + 2) >> 3][(f + 2) & 7] = vp;
                }
            }
            char* base = (char*)uA + (size_t)(oh * 4 + bg) * 589824 + (ow * 16 + bl) * 16;
            #pragma unroll
            for (int j = 0; j < 18; ++j) {
                const int ks = 36 * ch + 18 * cc + j;
                *(us8*)(base + (size_t)(ks >> 2) * 32768 + (size_t)(ks & 3) * 8192) = arr[j];
            }
        }
    }
}

// ---------------------------------------------------------------- kernel 2
// grid 512 = (xcd 8, oq 4, hi 16); 512 thr = 8 waves; wave wvn: l = lg8*8 + wvn.
__global__ __launch_bounds__(512, 4)
void mfma_fused(const unsigned short* __restrict__ uA,
                const float* __restrict__ w,
                const float* __restrict__ bias,
                float* __restrict__ out)
{
    __shared__ char smem[36864];   // W dbuf 2x18432B; epilogue Ls (16896B) overlays
    unsigned short* const wb0 = (unsigned short*)smem;
    unsigned short* const wb1 = (unsigned short*)(smem + 18432);

    const int blk  = blockIdx.x;
    const int xcd  = blk & 7;
    const int oq   = (blk >> 3) & 3;     // o0 = 32*oq
    const int hi   = blk >> 5;           // 0..15
    const int lg8  = xcd * 16 + hi;      // 0..127, 8 l's per block
    const int tid  = threadIdx.x;
    const int lane = tid & 63;
    const int wvn  = tid >> 6;           // 0..7 -> l = lg8*8 + wvn
    const int r    = lane & 15;
    const int g    = lane >> 4;
    const int oh   = lg8 >> 2;                   // block-uniform
    const int ow   = ((lg8 & 3) << 3) + wvn;     // l & 31
    const int o0   = 32 * oq;

    // ---- uA addressing (R7-R12 verified cells)
    const char* ubase = (const char*)uA + (size_t)oh * 2359296;
    const unsigned uoff = (unsigned)(g * 8192 + (ow * 16 + r) * 16);

    // ---- W loader: D = tid>>6 (=e), lL = (tid>>3)&7, o4 = tid&7
    const int D  = tid >> 6;
    const int lL = (tid >> 3) & 7;
    const int o4 = tid & 7;
    const float* wth = w + (size_t)D * 131072 + (lg8 * 8 + lL) * 128 + o0 + o4 * 4;

    // slot s = (o4>>2)*64 + rr*16 + rf, rf=(o4&3)*4+v; row = 72 ushorts (144B pad)
#define WSTORE(BUF, RT)                                                        \
    {   _Pragma("unroll")                                                      \
        for (int rr = 0; rr < 4; ++rr) {                                       \
            _Pragma("unroll")                                                  \
            for (int v = 0; v < 4; ++v) {                                      \
                const int s = (o4 >> 2) * 64 + rr * 16 + (o4 & 3) * 4 + v;     \
                (BUF)[s * 72 + lL * 8 + D] = f2bf((RT)[rr][v]);                \
            }                                                                  \
        }                                                                      \
    }
#define WLOAD(KT, RT)                                                          \
    {   _Pragma("unroll")                                                      \
        for (int rr = 0; rr < 4; ++rr)                                         \
            (RT)[rr] = *(const f32x4*)(wth + ((size_t)(KT) * 32 + 8 * rr) * 131072); \
    }
#define ULOAD(KT, CU)                                                          \
    {   _Pragma("unroll")                                                      \
        for (int mt = 0; mt < 4; ++mt)                                         \
            (CU)[mt] = *(const bf16x8*)(ubase + (size_t)(KT) * 32768 +         \
                                        (size_t)mt * 589824 + uoff);           \
    }

    // ---- B-fragment read offsets (ushort units), conflict-free-by-pad
    const int rdo0 = (g * 16 + r) * 72 + wvn * 8;
    const int rdo1 = (64 + g * 16 + r) * 72 + wvn * 8;

    f32x4 acc[4][2];
    #pragma unroll
    for (int mt = 0; mt < 4; ++mt) {
        acc[mt][0] = (f32x4){0.f, 0.f, 0.f, 0.f};
        acc[mt][1] = (f32x4){0.f, 0.f, 0.f, 0.f};
    }

    // ---- prologue: 2 W tiles + 2 uA tiles in flight
    f32x4 rA[4], rB[4];
    bf16x8 cuA[4], cuB[4];
    WLOAD(0, rA);
    WLOAD(1, rB);
    ULOAD(0, cuA);
    ULOAD(1, cuB);
    WSTORE(wb0, rA);
    __syncthreads();

    #pragma unroll
    for (int kt = 0; kt < 18; ++kt) {
        if (kt + 2 < 18) {
            if ((kt & 1) == 0) { WLOAD(kt + 2, rA); }
            else               { WLOAD(kt + 2, rB); }
        }
        if (kt + 1 < 18) {
            if ((kt & 1) == 0) { WSTORE(wb1, rB); }
            else               { WSTORE(wb0, rA); }
        }
        {
            const unsigned short* bb = (kt & 1) ? wb1 : wb0;
            const bf16x8 bf0 = *(const bf16x8*)(bb + rdo0);
            const bf16x8 bf1 = *(const bf16x8*)(bb + rdo1);
            #pragma unroll
            for (int mt = 0; mt < 4; ++mt) {
                const bf16x8 cu = (kt & 1) ? cuB[mt] : cuA[mt];
                acc[mt][0] = __builtin_amdgcn_mfma_f32_16x16x32_bf16(cu, bf0, acc[mt][0], 0, 0, 0);
                acc[mt][1] = __builtin_amdgcn_mfma_f32_16x16x32_bf16(cu, bf1, acc[mt][1], 0, 0, 0);
            }
        }
        if (kt + 2 < 18) {
            if ((kt & 1) == 0) { ULOAD(kt + 2, cuA); }
            else               { ULOAD(kt + 2, cuB); }
        }
        __syncthreads();
    }
#undef WSTORE
#undef WLOAD
#undef ULOAD

    // ---- epilogue: 4 mt-phases via LDS [o' 32][l~ 8][b~ 16], row stride 132 f32
    float* const Ls = (float*)smem;
    const int rb = tid & 15;             // b~
    const int ro = tid >> 4;             // o' 0..31
    #pragma unroll
    for (int p = 0; p < 4; ++p) {
        __syncthreads();
        #pragma unroll
        for (int n = 0; n < 2; ++n) {
            const int fidx = (16 * n + r) * 132 + wvn * 16 + 4 * g;
            *(f32x4*)&Ls[fidx] = acc[p][n];
        }
        __syncthreads();
        #pragma unroll
        for (int l4 = 0; l4 < 2; ++l4) {
            f32x4 v;
            #pragma unroll
            for (int j = 0; j < 4; ++j)
                v[j] = Ls[ro * 132 + (l4 * 4 + j) * 16 + rb];
            const int b = 16 * p + rb;
            const int o = o0 + ro;
            const int lbase = lg8 * 8 + l4 * 4;
            const f32x4 bz = *(const f32x4*)(bias + (o << 10) + lbase);
            v += bz;
            *(f32x4*)(out + (((size_t)(b * 128 + o)) << 10) + lbase) = v;
        }
    }
}

// ---------------------------------------------------------------- fp32 fallback (R1-verified)
__global__ __launch_bounds__(256, 4)
void lc2d_fp32(const float* __restrict__ x,
               const float* __restrict__ w,
               const float* __restrict__ bias,
               float* __restrict__ out)
{
    __shared__ float Us[36][68];
    __shared__ float Ws[36][128];
    const int blk = blockIdx.x;
    const int l  = ((blk & 7) << 7) | (blk >> 3);
    const int oh = l >> 5, ow = l & 31;
    const int tid = threadIdx.x;
    const int tx = tid & 15, ty = tid >> 4;
    const int sb = tid >> 2, sc = tid & 3;

    float acc[4][8];
    #pragma unroll
    for (int i = 0; i < 4; ++i)
        #pragma unroll
        for (int j = 0; j < 8; ++j) acc[i][j] = 0.f;

    for (int chn = 0; chn < 16; ++chn) {
        const int c0 = chn * 4;
        const float* xb = x + ((size_t)(sb * 64 + c0 + sc) << 10);
        #pragma unroll
        for (int ii = 0; ii < 3; ++ii) {
            const int y = oh + ii - 1;
            const bool yok = ((unsigned)y < 32u);
            #pragma unroll
            for (int jj = 0; jj < 3; ++jj) {
                const int z = ow + jj - 1;
                float v = 0.f;
                if (yok && ((unsigned)z < 32u)) v = xb[(y << 5) + z];
                Us[sc * 9 + ii * 3 + jj][sb] = v;
            }
        }
        const int dbase = c0 * 9;
        #pragma unroll
        for (int it = 0; it < 5; ++it) {
            const int idx = tid + it * 256;
            if (idx < 36 * 32) {
                const int kk = idx >> 5, o4 = idx & 31;
                const float4 v = *reinterpret_cast<const float4*>(
                    w + (((size_t)(dbase + kk) * 1024 + l) * 128 + o4 * 4));
                *reinterpret_cast<float4*>(&Ws[kk][o4 * 4]) = v;
            }
        }
        __syncthreads();
        #pragma unroll 6
        for (int kk = 0; kk < 36; ++kk) {
            const float4 ub = *reinterpret_cast<const float4*>(&Us[kk][ty * 4]);
            const float4 wa = *reinterpret_cast<const float4*>(&Ws[kk][tx * 4]);
            const float4 wb = *reinterpret_cast<const float4*>(&Ws[kk][tx * 4 + 64]);
            const float u[4]  = {ub.x, ub.y, ub.z, ub.w};
            const float a[4]  = {wa.x, wa.y, wa.z, wa.w};
            const float b2[4] = {wb.x, wb.y, wb.z, wb.w};
            #pragma unroll
            for (int bi = 0; bi < 4; ++bi)
                #pragma unroll
                for (int oi = 0; oi < 4; ++oi) {
                    acc[bi][oi]     += u[bi] * a[oi];
                    acc[bi][4 + oi] += u[bi] * b2[oi];
                }
        }
        __syncthreads();
    }

    float bs[8];
    #pragma unroll
    for (int oi = 0; oi < 4; ++oi) {
        bs[oi]     = bias[((tx * 4 + oi) << 10) + l];
        bs[4 + oi] = bias[((tx * 4 + 64 + oi) << 10) + l];
    }
    #pragma unroll
    for (int bi = 0; bi < 4; ++bi) {
        const int b = ty * 4 + bi;
        #pragma unroll
        for (int oi = 0; oi < 4; ++oi) {
            out[((b * 128 + tx * 4 + oi) << 10) + l]      = acc[bi][oi]     + bs[oi];
            out[((b * 128 + tx * 4 + 64 + oi) << 10) + l] = acc[bi][4 + oi] + bs[4 + oi];
        }
    }
}

// ---------------------------------------------------------------- launch
extern "C" void kernel_launch(void* const* d_in, const int* in_sizes, int n_in,
                              void* d_out, int out_size, void* d_ws, size_t ws_size,
                              hipStream_t stream) {
    const float* x    = (const float*)d_in[0];
    const float* w    = (const float*)d_in[1];
    const float* bias = (const float*)d_in[2];
    float* out        = (float*)d_out;

    const size_t UA_BYTES = 75497472ull;   // 32*4*18*4*8192

    if (d_ws && ws_size >= UA_BYTES) {
        unsigned short* uab = (unsigned short*)d_ws;
        u_kernel<<<dim3(256), dim3(256), 0, stream>>>(x, uab);
        mfma_fused<<<dim3(512), dim3(512), 0, stream>>>(uab, w, bias, out);
    } else {
        lc2d_fp32<<<dim3(1024), dim3(256), 0, stream>>>(x, w, bias, out);
    }
}

// Round 14
// 106.594 us; speedup vs baseline: 1.3507x; 1.1805x over previous
//
#include <hip/hip_runtime.h>
#include <hip/hip_bf16.h>

// TransposedLocallyConnected2D: out[b,o,l] = sum_d U[b,d,l] * W[d,l,o] + bias[o,l]
//   B=64, C=64, OC=128, L=1024, D=576 (d = c*9 + ii*3 + jj). Per-l 64x128x576 GEMM.
//
// R14 (on R13's verified structure):
//  - u_kernel: 512 threads (was 256) -> 8 waves/CU, gather work per thread halved
//    (item = (bl, ow) directly). Same LDS tile, same verified store layout.
//  - mfma: W loads nontemporal (stream-once; stop thrashing L2 against the
//    4x-reused uA working set: 64 blocks/XCD x 576KB uA vs 4MB L2);
//    s_setprio(1) around the MFMA cluster (2 co-resident blocks = role diversity).
//  - Everything else verbatim R13 (verified).

typedef __attribute__((ext_vector_type(8))) short bf16x8;
typedef __attribute__((ext_vector_type(4))) float f32x4;
typedef __attribute__((ext_vector_type(4))) unsigned short us4;
typedef __attribute__((ext_vector_type(8))) unsigned short us8;

__device__ __forceinline__ unsigned short f2bf(float f) {
    union { __hip_bfloat16 h; unsigned short u; } cv;
    cv.h = __float2bfloat16(f);
    return cv.u;
}

// ---------------------------------------------------------------- kernel 1
// grid 256 x 512 thr: blk -> ch (c-half), bg (b-quarter = mt), oh.
__global__ __launch_bounds__(512, 1)
void u_kernel(const float* __restrict__ x, unsigned short* __restrict__ uA)
{
    __shared__ unsigned short xs[3 * 32 * 16 * 36];   // [y][c][b][32z + 4 pad]

    const int blk = blockIdx.x;
    const int ch = blk & 1;
    const int bg = (blk >> 1) & 3;
    const int oh = blk >> 3;
    const int t  = threadIdx.x;

    // ---- stage x chunk: 16b x 32c x 3y x 32z, fully coalesced float4
    #pragma unroll
    for (int y = 0; y < 3; ++y) {
        const int yg = oh - 1 + y;
        const bool rowok = (unsigned)yg < 32u;   // block-uniform
        #pragma unroll
        for (int j = 0; j < 8; ++j) {
            const int idx2 = t + 512 * j;
            const int z4 = idx2 & 7;
            const int cl = (idx2 >> 3) & 31;
            const int bl = idx2 >> 8;
            float4 v = {0.f, 0.f, 0.f, 0.f};
            if (rowok)
                v = *(const float4*)(x + ((((16 * bg + bl) * 64 + 32 * ch + cl) * 32 + yg) << 5) + 4 * z4);
            *(us4*)&xs[((y * 32 + cl) * 16 + bl) * 36 + 4 * z4] =
                (us4){f2bf(v.x), f2bf(v.y), f2bf(v.z), f2bf(v.w)};
        }
    }
    __syncthreads();

    // ---- gather: item (bl = t&15, ow = t>>4), one item per thread
    const int bl = t & 15;
    const int ow = t >> 4;
    #pragma unroll
    for (int cc = 0; cc < 2; ++cc) {
        us8 arr[18];
        #pragma unroll
        for (int c16 = 0; c16 < 16; ++c16) {
            const int c = cc * 16 + c16;
            #pragma unroll
            for (int ii = 0; ii < 3; ++ii) {
                const unsigned short* xr = &xs[((ii * 32 + c) * 16 + bl) * 36];
                const unsigned short vm = (ow > 0)  ? xr[ow - 1] : (unsigned short)0;
                const unsigned short v0 = xr[ow];
                const unsigned short vp = (ow < 31) ? xr[ow + 1] : (unsigned short)0;
                const int f = c16 * 9 + ii * 3;      // compile-time after unroll
                arr[(f + 0) >> 3][(f + 0) & 7] = vm;
                arr[(f + 1) >> 3][(f + 1) & 7] = v0;
                arr[(f + 2) >> 3][(f + 2) & 7] = vp;
            }
        }
        char* base = (char*)uA + (size_t)(oh * 4 + bg) * 589824 + (ow * 16 + bl) * 16;
        #pragma unroll
        for (int j = 0; j < 18; ++j) {
            const int ks = 36 * ch + 18 * cc + j;
            *(us8*)(base + (size_t)(ks >> 2) * 32768 + (size_t)(ks & 3) * 8192) = arr[j];
        }
    }
}

// ---------------------------------------------------------------- kernel 2
// grid 512 = (xcd 8, oq 4, hi 16); 512 thr = 8 waves; wave wvn: l = lg8*8 + wvn.
__global__ __launch_bounds__(512, 4)
void mfma_fused(const unsigned short* __restrict__ uA,
                const float* __restrict__ w,
                const float* __restrict__ bias,
                float* __restrict__ out)
{
    __shared__ char smem[36864];   // W dbuf 2x18432B; epilogue Ls (16896B) overlays
    unsigned short* const wb0 = (unsigned short*)smem;
    unsigned short* const wb1 = (unsigned short*)(smem + 18432);

    const int blk  = blockIdx.x;
    const int xcd  = blk & 7;
    const int oq   = (blk >> 3) & 3;     // o0 = 32*oq
    const int hi   = blk >> 5;           // 0..15
    const int lg8  = xcd * 16 + hi;      // 0..127, 8 l's per block
    const int tid  = threadIdx.x;
    const int lane = tid & 63;
    const int wvn  = tid >> 6;           // 0..7 -> l = lg8*8 + wvn
    const int r    = lane & 15;
    const int g    = lane >> 4;
    const int oh   = lg8 >> 2;                   // block-uniform
    const int ow   = ((lg8 & 3) << 3) + wvn;     // l & 31
    const int o0   = 32 * oq;

    // ---- uA addressing (R7-R13 verified cells)
    const char* ubase = (const char*)uA + (size_t)oh * 2359296;
    const unsigned uoff = (unsigned)(g * 8192 + (ow * 16 + r) * 16);

    // ---- W loader: D = tid>>6 (=e), lL = (tid>>3)&7, o4 = tid&7
    const int D  = tid >> 6;
    const int lL = (tid >> 3) & 7;
    const int o4 = tid & 7;
    const float* wth = w + (size_t)D * 131072 + (lg8 * 8 + lL) * 128 + o0 + o4 * 4;

    // slot s = (o4>>2)*64 + rr*16 + rf, rf=(o4&3)*4+v; row = 72 ushorts (144B pad)
#define WSTORE(BUF, RT)                                                        \
    {   _Pragma("unroll")                                                      \
        for (int rr = 0; rr < 4; ++rr) {                                       \
            _Pragma("unroll")                                                  \
            for (int v = 0; v < 4; ++v) {                                      \
                const int s = (o4 >> 2) * 64 + rr * 16 + (o4 & 3) * 4 + v;     \
                (BUF)[s * 72 + lL * 8 + D] = f2bf((RT)[rr][v]);                \
            }                                                                  \
        }                                                                      \
    }
#define WLOAD(KT, RT)                                                          \
    {   _Pragma("unroll")                                                      \
        for (int rr = 0; rr < 4; ++rr)                                         \
            (RT)[rr] = __builtin_nontemporal_load(                             \
                (const f32x4*)(wth + ((size_t)(KT) * 32 + 8 * rr) * 131072));  \
    }
#define ULOAD(KT, CU)                                                          \
    {   _Pragma("unroll")                                                      \
        for (int mt = 0; mt < 4; ++mt)                                         \
            (CU)[mt] = *(const bf16x8*)(ubase + (size_t)(KT) * 32768 +         \
                                        (size_t)mt * 589824 + uoff);           \
    }

    // ---- B-fragment read offsets (ushort units), conflict-free-by-pad
    const int rdo0 = (g * 16 + r) * 72 + wvn * 8;
    const int rdo1 = (64 + g * 16 + r) * 72 + wvn * 8;

    f32x4 acc[4][2];
    #pragma unroll
    for (int mt = 0; mt < 4; ++mt) {
        acc[mt][0] = (f32x4){0.f, 0.f, 0.f, 0.f};
        acc[mt][1] = (f32x4){0.f, 0.f, 0.f, 0.f};
    }

    // ---- prologue: 2 W tiles + 2 uA tiles in flight
    f32x4 rA[4], rB[4];
    bf16x8 cuA[4], cuB[4];
    WLOAD(0, rA);
    WLOAD(1, rB);
    ULOAD(0, cuA);
    ULOAD(1, cuB);
    WSTORE(wb0, rA);
    __syncthreads();

    #pragma unroll
    for (int kt = 0; kt < 18; ++kt) {
        if (kt + 2 < 18) {
            if ((kt & 1) == 0) { WLOAD(kt + 2, rA); }
            else               { WLOAD(kt + 2, rB); }
        }
        if (kt + 1 < 18) {
            if ((kt & 1) == 0) { WSTORE(wb1, rB); }
            else               { WSTORE(wb0, rA); }
        }
        {
            const unsigned short* bb = (kt & 1) ? wb1 : wb0;
            const bf16x8 bf0 = *(const bf16x8*)(bb + rdo0);
            const bf16x8 bf1 = *(const bf16x8*)(bb + rdo1);
            __builtin_amdgcn_s_setprio(1);
            #pragma unroll
            for (int mt = 0; mt < 4; ++mt) {
                const bf16x8 cu = (kt & 1) ? cuB[mt] : cuA[mt];
                acc[mt][0] = __builtin_amdgcn_mfma_f32_16x16x32_bf16(cu, bf0, acc[mt][0], 0, 0, 0);
                acc[mt][1] = __builtin_amdgcn_mfma_f32_16x16x32_bf16(cu, bf1, acc[mt][1], 0, 0, 0);
            }
            __builtin_amdgcn_s_setprio(0);
        }
        if (kt + 2 < 18) {
            if ((kt & 1) == 0) { ULOAD(kt + 2, cuA); }
            else               { ULOAD(kt + 2, cuB); }
        }
        __syncthreads();
    }
#undef WSTORE
#undef WLOAD
#undef ULOAD

    // ---- epilogue: 4 mt-phases via LDS [o' 32][l~ 8][b~ 16], row stride 132 f32
    float* const Ls = (float*)smem;
    const int rb = tid & 15;             // b~
    const int ro = tid >> 4;             // o' 0..31
    #pragma unroll
    for (int p = 0; p < 4; ++p) {
        __syncthreads();
        #pragma unroll
        for (int n = 0; n < 2; ++n) {
            const int fidx = (16 * n + r) * 132 + wvn * 16 + 4 * g;
            *(f32x4*)&Ls[fidx] = acc[p][n];
        }
        __syncthreads();
        #pragma unroll
        for (int l4 = 0; l4 < 2; ++l4) {
            f32x4 v;
            #pragma unroll
            for (int j = 0; j < 4; ++j)
                v[j] = Ls[ro * 132 + (l4 * 4 + j) * 16 + rb];
            const int b = 16 * p + rb;
            const int o = o0 + ro;
            const int lbase = lg8 * 8 + l4 * 4;
            const f32x4 bz = *(const f32x4*)(bias + (o << 10) + lbase);
            v += bz;
            *(f32x4*)(out + (((size_t)(b * 128 + o)) << 10) + lbase) = v;
        }
    }
}

// ---------------------------------------------------------------- fp32 fallback (R1-verified)
__global__ __launch_bounds__(256, 4)
void lc2d_fp32(const float* __restrict__ x,
               const float* __restrict__ w,
               const float* __restrict__ bias,
               float* __restrict__ out)
{
    __shared__ float Us[36][68];
    __shared__ float Ws[36][128];
    const int blk = blockIdx.x;
    const int l  = ((blk & 7) << 7) | (blk >> 3);
    const int oh = l >> 5, ow = l & 31;
    const int tid = threadIdx.x;
    const int tx = tid & 15, ty = tid >> 4;
    const int sb = tid >> 2, sc = tid & 3;

    float acc[4][8];
    #pragma unroll
    for (int i = 0; i < 4; ++i)
        #pragma unroll
        for (int j = 0; j < 8; ++j) acc[i][j] = 0.f;

    for (int chn = 0; chn < 16; ++chn) {
        const int c0 = chn * 4;
        const float* xb = x + ((size_t)(sb * 64 + c0 + sc) << 10);
        #pragma unroll
        for (int ii = 0; ii < 3; ++ii) {
            const int y = oh + ii - 1;
            const bool yok = ((unsigned)y < 32u);
            #pragma unroll
            for (int jj = 0; jj < 3; ++jj) {
                const int z = ow + jj - 1;
                float v = 0.f;
                if (yok && ((unsigned)z < 32u)) v = xb[(y << 5) + z];
                Us[sc * 9 + ii * 3 + jj][sb] = v;
            }
        }
        const int dbase = c0 * 9;
        #pragma unroll
        for (int it = 0; it < 5; ++it) {
            const int idx = tid + it * 256;
            if (idx < 36 * 32) {
                const int kk = idx >> 5, o4 = idx & 31;
                const float4 v = *reinterpret_cast<const float4*>(
                    w + (((size_t)(dbase + kk) * 1024 + l) * 128 + o4 * 4));
                *reinterpret_cast<float4*>(&Ws[kk][o4 * 4]) = v;
            }
        }
        __syncthreads();
        #pragma unroll 6
        for (int kk = 0; kk < 36; ++kk) {
            const float4 ub = *reinterpret_cast<const float4*>(&Us[kk][ty * 4]);
            const float4 wa = *reinterpret_cast<const float4*>(&Ws[kk][tx * 4]);
            const float4 wb = *reinterpret_cast<const float4*>(&Ws[kk][tx * 4 + 64]);
            const float u[4]  = {ub.x, ub.y, ub.z, ub.w};
            const float a[4]  = {wa.x, wa.y, wa.z, wa.w};
            const float b2[4] = {wb.x, wb.y, wb.z, wb.w};
            #pragma unroll
            for (int bi = 0; bi < 4; ++bi)
                #pragma unroll
                for (int oi = 0; oi < 4; ++oi) {
                    acc[bi][oi]     += u[bi] * a[oi];
                    acc[bi][4 + oi] += u[bi] * b2[oi];
                }
        }
        __syncthreads();
    }

    float bs[8];
    #pragma unroll
    for (int oi = 0; oi < 4; ++oi) {
        bs[oi]     = bias[((tx * 4 + oi) << 10) + l];
        bs[4 + oi] = bias[((tx * 4 + 64 + oi) << 10) + l];
    }
    #pragma unroll
    for (int bi = 0; bi < 4; ++bi) {
        const int b = ty * 4 + bi;
        #pragma unroll
        for (int oi = 0; oi < 4; ++oi) {
            out[((b * 128 + tx * 4 + oi) << 10) + l]      = acc[bi][oi]     + bs[oi];
            out[((b * 128 + tx * 4 + 64 + oi) << 10) + l] = acc[bi][4 + oi] + bs[4 + oi];
        }
    }
}

// ---------------------------------------------------------------- launch
extern "C" void kernel_launch(void* const* d_in, const int* in_sizes, int n_in,
                              void* d_out, int out_size, void* d_ws, size_t ws_size,
                              hipStream_t stream) {
    const float* x    = (const float*)d_in[0];
    const float* w    = (const float*)d_in[1];
    const float* bias = (const float*)d_in[2];
    float* out        = (float*)d_out;

    const size_t UA_BYTES = 75497472ull;   // 32*4*18*4*8192

    if (d_ws && ws_size >= UA_BYTES) {
        unsigned short* uab = (unsigned short*)d_ws;
        u_kernel<<<dim3(256), dim3(512), 0, stream>>>(x, uab);
        mfma_fused<<<dim3(512), dim3(512), 0, stream>>>(uab, w, bias, out);
    } else {
        lc2d_fp32<<<dim3(1024), dim3(256), 0, stream>>>(x, w, bias, out);
    }
}